// Round 2
// baseline (213.397 us; speedup 1.0000x reference)
//
#include <hip/hip_runtime.h>
#include <math.h>

// Router: logits = z @ W^T + b ; top-2 sparse softmax.  z:[8192,4096]f32,
// W:[64,4096]f32, b:[64], k=2.
//
// R11: single fused kernel, zero workspace. R10 post-mortem: total was flat
// (211.7 vs 210.9) under a structural gemm rewrite, and no kernel of ours
// cracks the top-5 (all ~77us 512MB poison fills) -> each kernel <77us and
// ~150us of dur_us is fixed harness overhead. Remaining lever = the split-K
// tax: part buffer 33.5MB x2 round-trip (~11us) + 2nd dispatch + gap.
// Now: BM=32 -> grid 256 (1 block/CU), full K=4096 per block, each of 8
// waves owns ONE 16x16 tile (2 mt x 4 nt) -> logits finish in-register;
// bias + top-2 + sparse softmax fused in epilogue. K streamed in 16 chunks
// of 256 through LDS (z coalesced 1KB/wave-instr; W f32->limb inline,
// L2-hot 1MB). Ping-pong reg staging (A/B sets, static idx) so chunk c+1
// loads fly under chunk c compute. HBM floor: z 134MB + W 8MB + out 2MB
// ~= 23us.  Numerics identical to passing R5-R10: x = h + l*2^-11,
// 3 MFMA passes, recombine *2^-11; strict-> ascending top-2 scan.
// Frag layouts (verified R4-R8): A[m=lane&15][k=quad*8+j],
// B[n=lane&15][k=quad*8+j], D[row=quad*4+reg][col=lane&15].

typedef _Float16 f16x8 __attribute__((ext_vector_type(8)));
typedef _Float16 f16x4 __attribute__((ext_vector_type(4)));
typedef float    f32x4 __attribute__((ext_vector_type(4)));

constexpr int D_DIM = 4096;
constexpr int K_DIM = 64;
constexpr int BM    = 32;             // rows per block
constexpr int BLOCK = 512;            // 8 waves
constexpr int CK    = 256;            // K-chunk (f32)
constexpr int NCH   = D_DIM / CK;     // 16
constexpr int WSTR  = 264;            // W limb row stride, f16 (528 B)
constexpr int ZSTR  = 260;            // z row stride, f32 (1040 B, 16B-aligned)

// issue: fully-coalesced global loads (each wave-instr = one contiguous 1KB
// row-chunk: row = wv + i*8, 64 lanes x 16B).
#define ISSUE(c, zr, wr) do {                                                  \
    const float* zc_ = z + m0 * D_DIM + (c) * CK;                              \
    _Pragma("unroll")                                                          \
    for (int i = 0; i < 4; ++i)                                                \
        zr[i] = *(const f32x4*)(zc_ + (long)(wv + i * 8) * D_DIM + lane * 4);  \
    const float* wc_ = W + (c) * CK;                                           \
    _Pragma("unroll")                                                          \
    for (int i = 0; i < 8; ++i)                                                \
        wr[i] = *(const f32x4*)(wc_ + (long)(wv + i * 8) * D_DIM + lane * 4);  \
} while (0)

// park: regs -> LDS; W converted to RNE hi/lo f16 limbs (proven split).
#define PARK(zr, wr) do {                                                      \
    _Pragma("unroll")                                                          \
    for (int i = 0; i < 4; ++i)                                                \
        *(f32x4*)&zs[wv + i * 8][lane * 4] = zr[i];                            \
    _Pragma("unroll")                                                          \
    for (int i = 0; i < 8; ++i) {                                              \
        f16x4 h_, l_;                                                          \
        _Pragma("unroll")                                                      \
        for (int j = 0; j < 4; ++j) {                                          \
            _Float16 hh = (_Float16)wr[i][j];                                  \
            h_[j] = hh;                                                        \
            l_[j] = (_Float16)((wr[i][j] - (float)hh) * 2048.0f);              \
        }                                                                      \
        *(f16x4*)&Ws[0][wv + i * 8][lane * 4] = h_;                            \
        *(f16x4*)&Ws[1][wv + i * 8][lane * 4] = l_;                            \
    }                                                                          \
} while (0)

// compute: 8 K-steps of 32 from LDS; 3 MFMA/step (limb recombine later).
#define COMPUTE() do {                                                         \
    _Pragma("unroll")                                                          \
    for (int s = 0; s < CK / 32; ++s) {                                        \
        const int ko = s * 32 + quad * 8;                                      \
        const f32x4 a0 = *(const f32x4*)&zs[mt * 16 + m16][ko];                \
        const f32x4 a1 = *(const f32x4*)&zs[mt * 16 + m16][ko + 4];            \
        f16x8 ah, al;                                                          \
        _Pragma("unroll")                                                      \
        for (int j = 0; j < 4; ++j) {                                          \
            _Float16 h0 = (_Float16)a0[j];                                     \
            ah[j]     = h0;                                                    \
            al[j]     = (_Float16)((a0[j] - (float)h0) * 2048.0f);             \
            _Float16 h1 = (_Float16)a1[j];                                     \
            ah[j + 4] = h1;                                                    \
            al[j + 4] = (_Float16)((a1[j] - (float)h1) * 2048.0f);             \
        }                                                                      \
        const f16x8 bh = *(const f16x8*)&Ws[0][nt * 16 + m16][ko];             \
        const f16x8 bl = *(const f16x8*)&Ws[1][nt * 16 + m16][ko];             \
        accl = __builtin_amdgcn_mfma_f32_16x16x32_f16(al, bh, accl, 0, 0, 0);  \
        accl = __builtin_amdgcn_mfma_f32_16x16x32_f16(ah, bl, accl, 0, 0, 0);  \
        acch = __builtin_amdgcn_mfma_f32_16x16x32_f16(ah, bh, acch, 0, 0, 0);  \
    }                                                                          \
} while (0)

__global__ __launch_bounds__(BLOCK, 2) void router_fused(
    const float* __restrict__ z, const float* __restrict__ W,
    const float* __restrict__ bias, float* __restrict__ out)
{
    __shared__ __align__(16) _Float16 Ws[2][K_DIM][WSTR];   // 67.6 KB
    __shared__ __align__(16) float    zs[BM][ZSTR];         // 33.3 KB
    __shared__ float lg[BM][K_DIM + 1];                     // 8.3 KB
    __shared__ float sa1[BM], sa2[BM];
    __shared__ int   si1[BM], si2[BM];
    // total ~110 KB -> 1 block/CU, 8 waves (2/SIMD)

    const int tid  = threadIdx.x;
    const int lane = tid & 63;
    const int m16  = lane & 15;
    const int quad = lane >> 4;
    const int wv   = tid >> 6;          // 0..7
    const int mt   = wv >> 2;           // m-tile 0..1 (16 rows each)
    const int nt   = wv & 3;            // n-tile 0..3 (16 cols each)

    const long m0 = (long)blockIdx.x * BM;

    f32x4 zrA[4], wrA[8], zrB[4], wrB[8];     // ping-pong staging (96 VGPR)
    f32x4 acch = {0.f, 0.f, 0.f, 0.f};
    f32x4 accl = {0.f, 0.f, 0.f, 0.f};

    ISSUE(0, zrA, wrA);                       // chunk 0 flies immediately

#pragma unroll 1
    for (int cc = 0; cc < NCH / 2; ++cc) {
        // ---- chunk 2cc (set A) ----
        if (cc) __syncthreads();              // prev compute done reading LDS
        PARK(zrA, wrA);                       // waits A loads (vmcnt)
        ISSUE(2 * cc + 1, zrB, wrB);          // next chunk under compute
        __syncthreads();
        COMPUTE();
        // ---- chunk 2cc+1 (set B) ----
        __syncthreads();                      // all waves done reading LDS
        PARK(zrB, wrB);
        if (2 * cc + 2 < NCH) ISSUE(2 * cc + 2, zrA, wrA);
        __syncthreads();
        COMPUTE();
    }

    // ---- epilogue: logits -> LDS, bias, top-2, sparse softmax, store ----
    const float bv = bias[nt * 16 + m16];     // lane's column is fixed
#pragma unroll
    for (int r = 0; r < 4; ++r)
        lg[mt * 16 + quad * 4 + r][nt * 16 + m16] =
            acch[r] + accl[r] * 4.8828125e-4f + bv;
    __syncthreads();

    if (tid < BM) {   // strict >, ascending scan = lowest-index tie-break
        float m1 = -INFINITY, m2 = -INFINITY;
        int i1 = 0, i2 = 0;
        for (int j = 0; j < K_DIM; ++j) {
            float v = lg[tid][j];
            if (v > m1)      { m2 = m1; i2 = i1; m1 = v; i1 = j; }
            else if (v > m2) { m2 = v; i2 = j; }
        }
        float e2  = expf(m2 - m1);
        float inv = 1.f / (1.f + e2);
        sa1[tid] = inv; sa2[tid] = e2 * inv;
        si1[tid] = i1;  si2[tid] = i2;
    }
    __syncthreads();

    {   // 32 rows x 64 cols = 512 f32x4: exactly one per thread, coalesced
        const int r  = tid >> 4;
        const int c4 = (tid & 15) * 4;
        const int i1 = si1[r], i2 = si2[r];
        const float a1 = sa1[r], a2 = sa2[r];
        f32x4 v;
        v[0] = (c4 + 0 == i1) ? a1 : ((c4 + 0 == i2) ? a2 : 0.f);
        v[1] = (c4 + 1 == i1) ? a1 : ((c4 + 1 == i2) ? a2 : 0.f);
        v[2] = (c4 + 2 == i1) ? a1 : ((c4 + 2 == i2) ? a2 : 0.f);
        v[3] = (c4 + 3 == i1) ? a1 : ((c4 + 3 == i2) ? a2 : 0.f);
        *(f32x4*)(out + (m0 + r) * K_DIM + c4) = v;
    }
}

extern "C" void kernel_launch(void* const* d_in, const int* in_sizes, int n_in,
                              void* d_out, int out_size, void* d_ws, size_t ws_size,
                              hipStream_t stream) {
    const float* z = (const float*)d_in[0];
    const float* W = (const float*)d_in[1];
    const float* b = (const float*)d_in[2];
    float* out  = (float*)d_out;
    const int N = in_sizes[0] / D_DIM;           // 8192
    (void)d_ws; (void)ws_size; (void)n_in; (void)out_size;

    router_fused<<<dim3(N / BM), dim3(BLOCK), 0, stream>>>(z, W, b, out);
}